// Round 1
// baseline (125.816 us; speedup 1.0000x reference)
//
#include <hip/hip_runtime.h>

#define HDIM 256
#define COLSUM_BLOCKS 256

// Stage 1a: histogram of src indices.
__global__ void k_count(const int* __restrict__ src, int E, unsigned int* __restrict__ counts) {
    int e = blockIdx.x * blockDim.x + threadIdx.x;
    if (e < E) atomicAdd(&counts[src[e]], 1u);
}

// Stage 1b: partial weighted column sums: partials[b][h] = sum over this block's rows of counts[n]*x_src[n][h].
// Block = 256 threads = 4 rows per iteration (rowOff 0..3) x 64 float4 column-groups. Coalesced 4KB/row-iter.
__global__ void k_colsum_partial(const float4* __restrict__ x4,
                                 const unsigned int* __restrict__ counts,
                                 int N, float* __restrict__ partials) {
    int colgrp = threadIdx.x & 63;   // which float4 within the row
    int rowOff = threadIdx.x >> 6;   // 0..3
    float4 acc = make_float4(0.f, 0.f, 0.f, 0.f);
    for (int n = blockIdx.x * 4 + rowOff; n < N; n += gridDim.x * 4) {
        float c = (float)counts[n];           // broadcast-ish, L2/L1 hit
        float4 x = x4[(size_t)n * 64 + colgrp];
        acc.x += c * x.x; acc.y += c * x.y; acc.z += c * x.z; acc.w += c * x.w;
    }
    __shared__ float s[4 * HDIM];
    int col = colgrp * 4;
    s[rowOff * HDIM + col + 0] = acc.x;
    s[rowOff * HDIM + col + 1] = acc.y;
    s[rowOff * HDIM + col + 2] = acc.z;
    s[rowOff * HDIM + col + 3] = acc.w;
    __syncthreads();
    int tid = threadIdx.x;
    partials[(size_t)blockIdx.x * HDIM + tid] =
        s[tid] + s[HDIM + tid] + s[2 * HDIM + tid] + s[3 * HDIM + tid];
}

// Stage 1c: deterministic reduction of block partials -> left_sum[256].
__global__ void k_reduce_partials(const float* __restrict__ partials, int nblk,
                                  float* __restrict__ left_sum) {
    int h = threadIdx.x;
    float acc = 0.f;
    for (int b = 0; b < nblk; ++b) acc += partials[(size_t)b * HDIM + h];
    left_sum[h] = acc;
}

// Stage 2: v = R @ left_sum (256x256 matvec, one block, row per thread).
__global__ void k_matvec(const float* __restrict__ Rm, const float* __restrict__ ls,
                         float* __restrict__ v) {
    __shared__ float lss[HDIM];
    int i = threadIdx.x;
    lss[i] = ls[i];
    __syncthreads();
    const float4* R4 = (const float4*)(Rm + (size_t)i * HDIM);
    float acc = 0.f;
    #pragma unroll
    for (int j = 0; j < 64; ++j) {
        float4 r = R4[j];
        acc += r.x * lss[4 * j] + r.y * lss[4 * j + 1] + r.z * lss[4 * j + 2] + r.w * lss[4 * j + 3];
    }
    v[i] = acc;
}

// Stage 3a: t[n] = dot(x_trg[n], v). One wave (64 lanes) per row, float4 loads (1KB coalesced per row).
__global__ void k_rowdot(const float4* __restrict__ x4, const float* __restrict__ v,
                         int N, float* __restrict__ t) {
    __shared__ float4 vs[64];
    int tid = threadIdx.x;
    if (tid < 64) vs[tid] = ((const float4*)v)[tid];
    __syncthreads();
    int lane = tid & 63;
    int wid = tid >> 6;            // 4 waves per block = 4 rows
    int n = blockIdx.x * 4 + wid;
    if (n < N) {
        float4 x = x4[(size_t)n * 64 + lane];
        float4 vv = vs[lane];
        float d = x.x * vv.x + x.y * vv.y + x.z * vv.z + x.w * vv.w;
        #pragma unroll
        for (int off = 32; off > 0; off >>= 1) d += __shfl_down(d, off, 64);
        if (lane == 0) t[n] = d;
    }
}

// Stage 3b: out[e] = t[trg[e]] — gather from a 200KB L2-resident table.
__global__ void k_gather(const int* __restrict__ trg, int E, const float* __restrict__ t,
                         float* __restrict__ out) {
    int e = blockIdx.x * blockDim.x + threadIdx.x;
    if (e < E) out[e] = t[trg[e]];
}

extern "C" void kernel_launch(void* const* d_in, const int* in_sizes, int n_in,
                              void* d_out, int out_size, void* d_ws, size_t ws_size,
                              hipStream_t stream) {
    const float* x_src = (const float*)d_in[0];
    const float* x_trg = (const float*)d_in[1];
    const float* Rm    = (const float*)d_in[2];
    const int*   edge  = (const int*)d_in[3];   // int inputs arrive as int32; [0..E)=src, [E..2E)=trg
    float* out = (float*)d_out;

    const int N_src = in_sizes[0] / HDIM;
    const int N_trg = in_sizes[1] / HDIM;
    const int E     = in_sizes[3] / 2;

    // Workspace carve-out (256B-aligned slices).
    char* ws = (char*)d_ws;
    size_t off = 0;
    auto alloc = [&](size_t bytes) -> void* {
        void* p = ws + off;
        off = (off + bytes + 255) & ~(size_t)255;
        return p;
    };
    unsigned int* counts = (unsigned int*)alloc((size_t)N_src * sizeof(unsigned int));
    float* partials      = (float*)alloc((size_t)COLSUM_BLOCKS * HDIM * sizeof(float));
    float* left_sum      = (float*)alloc(HDIM * sizeof(float));
    float* v             = (float*)alloc(HDIM * sizeof(float));
    float* t             = (float*)alloc((size_t)N_trg * sizeof(float));
    (void)ws_size; (void)n_in; (void)out_size;

    // counts accumulates -> must be zeroed every call (graph-capture-safe async memset).
    hipMemsetAsync(counts, 0, (size_t)N_src * sizeof(unsigned int), stream);

    k_count<<<(E + 255) / 256, 256, 0, stream>>>(edge, E, counts);
    k_colsum_partial<<<COLSUM_BLOCKS, 256, 0, stream>>>((const float4*)x_src, counts, N_src, partials);
    k_reduce_partials<<<1, HDIM, 0, stream>>>(partials, COLSUM_BLOCKS, left_sum);
    k_matvec<<<1, HDIM, 0, stream>>>(Rm, left_sum, v);
    k_rowdot<<<(N_trg + 3) / 4, 256, 0, stream>>>((const float4*)x_trg, v, N_trg, t);
    k_gather<<<(E + 255) / 256, 256, 0, stream>>>(edge + E, E, t, out);
}

// Round 2
// 67.096 us; speedup vs baseline: 1.8752x; 1.8752x over previous
//
#include <hip/hip_runtime.h>

#define HDIM 256
#define NBLK 1024   // colsum partial blocks (compile-time so the reducer fully unrolls)

// Stage 1a: histogram of src indices (integer atomics -> deterministic).
__global__ void k_count(const int* __restrict__ src, int E, unsigned int* __restrict__ counts) {
    int e = blockIdx.x * blockDim.x + threadIdx.x;
    if (e < E) atomicAdd(&counts[src[e]], 1u);
}

// Stage 1b: partial weighted column sums: partials[b][h] = sum over this block's rows of counts[n]*x_src[n][h].
// Block = 256 threads = 4 rows per iteration x 64 float4 column-groups. Coalesced 4KB per row-iter.
__global__ void k_colsum_partial(const float4* __restrict__ x4,
                                 const unsigned int* __restrict__ counts,
                                 int N, float* __restrict__ partials) {
    int colgrp = threadIdx.x & 63;   // which float4 within the row
    int rowOff = threadIdx.x >> 6;   // 0..3
    float4 acc = make_float4(0.f, 0.f, 0.f, 0.f);
    for (int n = blockIdx.x * 4 + rowOff; n < N; n += NBLK * 4) {
        float c = (float)counts[n];           // 64-lane broadcast load, L2-hit
        float4 x = x4[(size_t)n * 64 + colgrp];
        acc.x += c * x.x; acc.y += c * x.y; acc.z += c * x.z; acc.w += c * x.w;
    }
    __shared__ float s[4 * HDIM];
    int col = colgrp * 4;
    s[rowOff * HDIM + col + 0] = acc.x;
    s[rowOff * HDIM + col + 1] = acc.y;
    s[rowOff * HDIM + col + 2] = acc.z;
    s[rowOff * HDIM + col + 3] = acc.w;
    __syncthreads();
    int tid = threadIdx.x;
    partials[(size_t)blockIdx.x * HDIM + tid] =
        s[tid] + s[HDIM + tid] + s[2 * HDIM + tid] + s[3 * HDIM + tid];
}

// Stage 1c+2 fused: left_sum[h] = sum_b partials[b][h]; v = R @ left_sum.
// One block, 1024 threads = (q=0..3) x (h=0..255). Compile-time trip counts,
// unrolled -> many loads in flight; 16 waves for TLP.
__global__ __launch_bounds__(1024)
void k_reduce_matvec(const float* __restrict__ partials,
                     const float* __restrict__ Rm,
                     float* __restrict__ v) {
    __shared__ float red[4][HDIM];
    __shared__ float lss[HDIM];
    const int tid = threadIdx.x;
    const int h = tid & (HDIM - 1);
    const int q = tid >> 8;   // 0..3

    // Phase 1: each (q,h) sums NBLK/4 = 256 partials, coalesced across the wave.
    const float* p = partials + (size_t)q * (NBLK / 4) * HDIM + h;
    float acc = 0.f;
    #pragma unroll 16
    for (int b = 0; b < NBLK / 4; ++b) acc += p[(size_t)b * HDIM];
    red[q][h] = acc;
    __syncthreads();
    if (q == 0) lss[h] = red[0][h] + red[1][h] + red[2][h] + red[3][h];
    __syncthreads();

    // Phase 2: matvec, 4 threads per output row (row = h, quarter q).
    const float4* R4 = (const float4*)(Rm + (size_t)h * HDIM);
    float a = 0.f;
    #pragma unroll
    for (int j = q * 16; j < q * 16 + 16; ++j) {
        float4 r = R4[j];
        a += r.x * lss[4 * j] + r.y * lss[4 * j + 1] + r.z * lss[4 * j + 2] + r.w * lss[4 * j + 3];
    }
    red[q][h] = a;
    __syncthreads();
    if (q == 0) v[h] = red[0][h] + red[1][h] + red[2][h] + red[3][h];
}

// Stage 3a: t[n] = dot(x_trg[n], v). One wave per row, float4 loads (1KB coalesced per row).
__global__ void k_rowdot(const float4* __restrict__ x4, const float* __restrict__ v,
                         int N, float* __restrict__ t) {
    __shared__ float4 vs[64];
    int tid = threadIdx.x;
    if (tid < 64) vs[tid] = ((const float4*)v)[tid];
    __syncthreads();
    int lane = tid & 63;
    int wid = tid >> 6;            // 4 waves per block = 4 rows
    int n = blockIdx.x * 4 + wid;
    if (n < N) {
        float4 x = x4[(size_t)n * 64 + lane];
        float4 vv = vs[lane];
        float d = x.x * vv.x + x.y * vv.y + x.z * vv.z + x.w * vv.w;
        #pragma unroll
        for (int off = 32; off > 0; off >>= 1) d += __shfl_down(d, off, 64);
        if (lane == 0) t[n] = d;
    }
}

// Stage 3b: out[e] = t[trg[e]] — gather from a 200KB L2-resident table.
__global__ void k_gather(const int* __restrict__ trg, int E, const float* __restrict__ t,
                         float* __restrict__ out) {
    int e = blockIdx.x * blockDim.x + threadIdx.x;
    if (e < E) out[e] = t[trg[e]];
}

extern "C" void kernel_launch(void* const* d_in, const int* in_sizes, int n_in,
                              void* d_out, int out_size, void* d_ws, size_t ws_size,
                              hipStream_t stream) {
    const float* x_src = (const float*)d_in[0];
    const float* x_trg = (const float*)d_in[1];
    const float* Rm    = (const float*)d_in[2];
    const int*   edge  = (const int*)d_in[3];   // [0..E)=src, [E..2E)=trg
    float* out = (float*)d_out;

    const int N_src = in_sizes[0] / HDIM;
    const int N_trg = in_sizes[1] / HDIM;
    const int E     = in_sizes[3] / 2;

    // Workspace carve-out (256B-aligned slices).
    char* ws = (char*)d_ws;
    size_t off = 0;
    auto alloc = [&](size_t bytes) -> void* {
        void* p = ws + off;
        off = (off + bytes + 255) & ~(size_t)255;
        return p;
    };
    unsigned int* counts = (unsigned int*)alloc((size_t)N_src * sizeof(unsigned int));
    float* partials      = (float*)alloc((size_t)NBLK * HDIM * sizeof(float));
    float* v             = (float*)alloc(HDIM * sizeof(float));
    float* t             = (float*)alloc((size_t)N_trg * sizeof(float));
    (void)ws_size; (void)n_in; (void)out_size;

    // counts accumulates -> zero it every call (graph-capture-safe async memset).
    hipMemsetAsync(counts, 0, (size_t)N_src * sizeof(unsigned int), stream);

    k_count<<<(E + 255) / 256, 256, 0, stream>>>(edge, E, counts);
    k_colsum_partial<<<NBLK, 256, 0, stream>>>((const float4*)x_src, counts, N_src, partials);
    k_reduce_matvec<<<1, 1024, 0, stream>>>(partials, Rm, v);
    k_rowdot<<<(N_trg + 3) / 4, 256, 0, stream>>>((const float4*)x_trg, v, N_trg, t);
    k_gather<<<(E + 255) / 256, 256, 0, stream>>>(edge + E, E, t, out);
}

// Round 3
// 65.939 us; speedup vs baseline: 1.9081x; 1.0176x over previous
//
#include <hip/hip_runtime.h>

#define HDIM 256
#define NBLK 1024   // colsum partial blocks (compile-time so the reducer fully unrolls)

// Stage 0: zero the histogram (the runtime's fillBufferAligned blit costs ~39us flat;
// a hand-rolled 200KB zero kernel is ~2us).
__global__ void k_zero(uint4* __restrict__ p, int n4) {
    int i = blockIdx.x * blockDim.x + threadIdx.x;
    if (i < n4) p[i] = make_uint4(0u, 0u, 0u, 0u);
}

// Stage 1a: histogram of src indices (integer atomics -> deterministic).
__global__ void k_count(const int* __restrict__ src, int E, unsigned int* __restrict__ counts) {
    int e = blockIdx.x * blockDim.x + threadIdx.x;
    if (e < E) atomicAdd(&counts[src[e]], 1u);
}

// Stage 1b: partial weighted column sums: partials[b][h] = sum over this block's rows of counts[n]*x_src[n][h].
// Block = 256 threads = 4 rows per iteration x 64 float4 column-groups. Coalesced 4KB per row-iter.
__global__ void k_colsum_partial(const float4* __restrict__ x4,
                                 const unsigned int* __restrict__ counts,
                                 int N, float* __restrict__ partials) {
    int colgrp = threadIdx.x & 63;   // which float4 within the row
    int rowOff = threadIdx.x >> 6;   // 0..3
    float4 acc = make_float4(0.f, 0.f, 0.f, 0.f);
    for (int n = blockIdx.x * 4 + rowOff; n < N; n += NBLK * 4) {
        float c = (float)counts[n];           // 64-lane broadcast load, L2-hit
        float4 x = x4[(size_t)n * 64 + colgrp];
        acc.x += c * x.x; acc.y += c * x.y; acc.z += c * x.z; acc.w += c * x.w;
    }
    __shared__ float s[4 * HDIM];
    int col = colgrp * 4;
    s[rowOff * HDIM + col + 0] = acc.x;
    s[rowOff * HDIM + col + 1] = acc.y;
    s[rowOff * HDIM + col + 2] = acc.z;
    s[rowOff * HDIM + col + 3] = acc.w;
    __syncthreads();
    int tid = threadIdx.x;
    partials[(size_t)blockIdx.x * HDIM + tid] =
        s[tid] + s[HDIM + tid] + s[2 * HDIM + tid] + s[3 * HDIM + tid];
}

// Stage 1c+2 fused: left_sum[h] = sum_b partials[b][h]; v = R @ left_sum.
// One block, 1024 threads = (q=0..3) x (h=0..255). Compile-time trip counts,
// unrolled -> many loads in flight; 16 waves for TLP.
__global__ __launch_bounds__(1024)
void k_reduce_matvec(const float* __restrict__ partials,
                     const float* __restrict__ Rm,
                     float* __restrict__ v) {
    __shared__ float red[4][HDIM];
    __shared__ float lss[HDIM];
    const int tid = threadIdx.x;
    const int h = tid & (HDIM - 1);
    const int q = tid >> 8;   // 0..3

    // Phase 1: each (q,h) sums NBLK/4 = 256 partials, coalesced across the wave.
    const float* p = partials + (size_t)q * (NBLK / 4) * HDIM + h;
    float acc = 0.f;
    #pragma unroll 16
    for (int b = 0; b < NBLK / 4; ++b) acc += p[(size_t)b * HDIM];
    red[q][h] = acc;
    __syncthreads();
    if (q == 0) lss[h] = red[0][h] + red[1][h] + red[2][h] + red[3][h];
    __syncthreads();

    // Phase 2: matvec, 4 threads per output row (row = h, quarter q).
    const float4* R4 = (const float4*)(Rm + (size_t)h * HDIM);
    float a = 0.f;
    #pragma unroll
    for (int j = q * 16; j < q * 16 + 16; ++j) {
        float4 r = R4[j];
        a += r.x * lss[4 * j] + r.y * lss[4 * j + 1] + r.z * lss[4 * j + 2] + r.w * lss[4 * j + 3];
    }
    red[q][h] = a;
    __syncthreads();
    if (q == 0) v[h] = red[0][h] + red[1][h] + red[2][h] + red[3][h];
}

// Stage 3a: t[n] = dot(x_trg[n], v). One wave per row, float4 loads (1KB coalesced per row).
__global__ void k_rowdot(const float4* __restrict__ x4, const float* __restrict__ v,
                         int N, float* __restrict__ t) {
    __shared__ float4 vs[64];
    int tid = threadIdx.x;
    if (tid < 64) vs[tid] = ((const float4*)v)[tid];
    __syncthreads();
    int lane = tid & 63;
    int wid = tid >> 6;            // 4 waves per block = 4 rows
    int n = blockIdx.x * 4 + wid;
    if (n < N) {
        float4 x = x4[(size_t)n * 64 + lane];
        float4 vv = vs[lane];
        float d = x.x * vv.x + x.y * vv.y + x.z * vv.z + x.w * vv.w;
        #pragma unroll
        for (int off = 32; off > 0; off >>= 1) d += __shfl_down(d, off, 64);
        if (lane == 0) t[n] = d;
    }
}

// Stage 3b: out[e] = t[trg[e]] — gather from a 200KB L2-resident table.
__global__ void k_gather(const int* __restrict__ trg, int E, const float* __restrict__ t,
                         float* __restrict__ out) {
    int e = blockIdx.x * blockDim.x + threadIdx.x;
    if (e < E) out[e] = t[trg[e]];
}

extern "C" void kernel_launch(void* const* d_in, const int* in_sizes, int n_in,
                              void* d_out, int out_size, void* d_ws, size_t ws_size,
                              hipStream_t stream) {
    const float* x_src = (const float*)d_in[0];
    const float* x_trg = (const float*)d_in[1];
    const float* Rm    = (const float*)d_in[2];
    const int*   edge  = (const int*)d_in[3];   // [0..E)=src, [E..2E)=trg
    float* out = (float*)d_out;

    const int N_src = in_sizes[0] / HDIM;
    const int N_trg = in_sizes[1] / HDIM;
    const int E     = in_sizes[3] / 2;

    // Workspace carve-out (256B-aligned slices).
    char* ws = (char*)d_ws;
    size_t off = 0;
    auto alloc = [&](size_t bytes) -> void* {
        void* p = ws + off;
        off = (off + bytes + 255) & ~(size_t)255;
        return p;
    };
    unsigned int* counts = (unsigned int*)alloc((size_t)N_src * sizeof(unsigned int));
    float* partials      = (float*)alloc((size_t)NBLK * HDIM * sizeof(float));
    float* v             = (float*)alloc(HDIM * sizeof(float));
    float* t             = (float*)alloc((size_t)N_trg * sizeof(float));
    (void)ws_size; (void)n_in; (void)out_size;

    // counts accumulates -> zero it every call with our own kernel
    // (hipMemsetAsync's fillBufferAligned blit has a ~39us fixed cost).
    const int n4 = (N_src + 3) / 4;   // counts buffer is 256B-aligned, uint4-safe
    k_zero<<<(n4 + 255) / 256, 256, 0, stream>>>((uint4*)counts, n4);

    k_count<<<(E + 255) / 256, 256, 0, stream>>>(edge, E, counts);
    k_colsum_partial<<<NBLK, 256, 0, stream>>>((const float4*)x_src, counts, N_src, partials);
    k_reduce_matvec<<<1, 1024, 0, stream>>>(partials, Rm, v);
    k_rowdot<<<(N_trg + 3) / 4, 256, 0, stream>>>((const float4*)x_trg, v, N_trg, t);
    k_gather<<<(E + 255) / 256, 256, 0, stream>>>(edge + E, E, t, out);
}